// Round 2
// baseline (117.684 us; speedup 1.0000x reference)
//
#include <hip/hip_runtime.h>
#include <math.h>

#define NH 512
#define NO 512
#define BT_TOT 256
#define HID 64
#define OUTD 128

__device__ __forceinline__ float wave_sum(float v) {
    #pragma unroll
    for (int off = 32; off > 0; off >>= 1) v += __shfl_xor(v, off, 64);
    return v;
}

// Tables: T[pt] = (-2x, -2y, -2z, x^2+y^2+z^2) so that
// d^2(p, pt) = ||p||^2 + fma(pz,T.z, fma(py,T.y, fma(px,T.x, T.w)))
__global__ __launch_bounds__(512) void ie_prep(
    const float* __restrict__ h_in, const float* __restrict__ o_in,
    float4* __restrict__ Th, float4* __restrict__ To)
{
    const int bt = blockIdx.x, t = threadIdx.x;
    const float* hp = h_in + ((size_t)bt * NH + t) * 3;
    const float* op = o_in + ((size_t)bt * NO + t) * 3;
    float hx = hp[0], hy = hp[1], hz = hp[2];
    float ox = op[0], oy = op[1], oz = op[2];
    Th[(size_t)bt * NH + t] = make_float4(-2.f*hx, -2.f*hy, -2.f*hz, hx*hx + hy*hy + hz*hz);
    To[(size_t)bt * NO + t] = make_float4(-2.f*ox, -2.f*oy, -2.f*oz, ox*ox + oy*oy + oz*oz);
}

__global__ __launch_bounds__(512) void ie_main(
    const float* __restrict__ h_in, const float* __restrict__ o_in,
    const float* __restrict__ sh_in,
    const float4* __restrict__ Th, const float4* __restrict__ To,
    const float* __restrict__ W1, const float* __restrict__ b1,
    const float* __restrict__ W2, const float* __restrict__ b2,
    float* __restrict__ out)
{
    __shared__ float lds[512];
    __shared__ float wred[5][8];
    __shared__ float feats[16];
    __shared__ float hidden[HID];

    const int bt = blockIdx.x, t = threadIdx.x;
    const int wave = t >> 6, lane = t & 63;

    // self coords: human t (pass 1 query) and object t (pass 2 query)
    const float* hp = h_in + ((size_t)bt * NH + t) * 3;
    const float px = hp[0], py = hp[1], pz = hp[2];
    const float hh = px*px + py*py + pz*pz;
    const float* op = o_in + ((size_t)bt * NO + t) * 3;
    const float qx = op[0], qy = op[1], qz = op[2];
    const float oo = qx*qx + qy*qy + qz*qz;

    const float4* __restrict__ to = To + (size_t)bt * NO;  // uniform-index stream
    const float4* __restrict__ th = Th + (size_t)bt * NH;

    // pass1 (human->object min+argmin) and pass2 (object->human min), fused
    float bA = 1e30f, bB = 1e30f, bC = 1e30f, bD = 1e30f;
    int   iA = 0,     iB = 1,     iC = 2,     iD = 3;
    float cA = 1e30f, cB = 1e30f, cC = 1e30f, cD = 1e30f;

    #pragma unroll 2
    for (int m = 0; m < NO; m += 4) {
        float4 q0 = to[m],   q1 = to[m+1], q2 = to[m+2], q3 = to[m+3];
        float4 r0 = th[m],   r1 = th[m+1], r2 = th[m+2], r3 = th[m+3];

        float a0 = fmaf(pz, q0.z, fmaf(py, q0.y, fmaf(px, q0.x, q0.w)));
        float a1 = fmaf(pz, q1.z, fmaf(py, q1.y, fmaf(px, q1.x, q1.w)));
        float a2 = fmaf(pz, q2.z, fmaf(py, q2.y, fmaf(px, q2.x, q2.w)));
        float a3 = fmaf(pz, q3.z, fmaf(py, q3.y, fmaf(px, q3.x, q3.w)));
        if (a0 < bA) { bA = a0; iA = m;     }
        if (a1 < bB) { bB = a1; iB = m + 1; }
        if (a2 < bC) { bC = a2; iC = m + 2; }
        if (a3 < bD) { bD = a3; iD = m + 3; }

        float e0 = fmaf(qz, r0.z, fmaf(qy, r0.y, fmaf(qx, r0.x, r0.w)));
        float e1 = fmaf(qz, r1.z, fmaf(qy, r1.y, fmaf(qx, r1.x, r1.w)));
        float e2 = fmaf(qz, r2.z, fmaf(qy, r2.y, fmaf(qx, r2.x, r2.w)));
        float e3 = fmaf(qz, r3.z, fmaf(qy, r3.y, fmaf(qx, r3.x, r3.w)));
        cA = fminf(cA, e0);
        cB = fminf(cB, e1);
        cC = fminf(cC, e2);
        cD = fminf(cD, e3);
    }

    // combine pass-1 trackers, first-index tie-break (iA<iB<iC<iD per residue)
    float best = bA; int bm = iA;
    if (bB < best || (bB == best && iB < bm)) { best = bB; bm = iB; }
    if (bC < best || (bC == best && iC < bm)) { best = bC; bm = iC; }
    if (bD < best || (bD == best && iD < bm)) { best = bD; bm = iD; }

    const float dmin_t = sqrtf(fmaxf(hh + best, 0.0f));
    const float cmin   = fminf(fminf(cA, cB), fminf(cC, cD));
    const float dmo_t  = sqrtf(fmaxf(oo + cmin, 0.0f));

    // dir_h2o from actual coordinate differences (matches reference _safe_norm)
    const float* onn = o_in + ((size_t)bt * NO + bm) * 3;
    const float vx = onn[0] - px, vy = onn[1] - py, vz = onn[2] - pz;
    const float n2 = vx*vx + vy*vy + vz*vz;
    const float inv = 1.0f / sqrtf(fmaxf(n2, 1e-6f));
    const float w_t = expf(-dmin_t * 20.0f) * sh_in[(size_t)bt * NH + t];

    // ---- reductions set 1: w, dir.xyz, dmin_o (shuffle + tiny LDS) ----
    {
        float s0 = wave_sum(w_t);
        float s1 = wave_sum(vx * inv);
        float s2 = wave_sum(vy * inv);
        float s3 = wave_sum(vz * inv);
        float s4 = wave_sum(dmo_t);
        if (lane == 0) {
            wred[0][wave] = s0; wred[1][wave] = s1; wred[2][wave] = s2;
            wred[3][wave] = s3; wred[4][wave] = s4;
        }
    }
    __syncthreads();
    if (t < 5) {
        float s = 0.f;
        #pragma unroll
        for (int w = 0; w < 8; w++) s += wred[t][w];
        const int   slot[5]  = {5, 6, 7, 8, 9};
        const float scale[5] = {1.f/NH, 1.f/NH, 1.f/NH, 1.f/NH, 1.f/NO};
        feats[slot[t]] = s * scale[t];
    }
    __syncthreads();

    // ---- bitonic sort of dmin_h: registers + shuffles; LDS only for j>=64 ----
    float v = dmin_t;
    for (int k2 = 2; k2 <= 512; k2 <<= 1) {
        for (int j = k2 >> 1; j > 0; j >>= 1) {
            const bool up = ((t & k2) == 0);
            float pv;
            if (j >= 64) {
                lds[t] = v;
                __syncthreads();
                pv = lds[t ^ j];
                __syncthreads();
            } else {
                pv = __shfl_xor(v, j, 64);
            }
            const bool keepmin = (up == ((t & j) == 0));
            v = keepmin ? fminf(v, pv) : fmaxf(v, pv);
        }
    }

    // ---- reductions set 2: prefix means over sorted values ----
    {
        float s0 = wave_sum(t < 102 ? v : 0.f);
        float s1 = wave_sum(t < 256 ? v : 0.f);
        float s2 = wave_sum(t < 410 ? v : 0.f);
        float s3 = wave_sum(v);
        if (lane == 0) {
            wred[0][wave] = s0; wred[1][wave] = s1;
            wred[2][wave] = s2; wred[3][wave] = s3;
        }
        if (t == 0) feats[1] = v;  // global min (sorted)
    }
    __syncthreads();
    if (t < 4) {
        float s = 0.f;
        #pragma unroll
        for (int w = 0; w < 8; w++) s += wred[t][w];
        const int   slot[4]  = {2, 3, 4, 0};
        const float scale[4] = {1.f/102.f, 1.f/256.f, 1.f/410.f, 1.f/NH};
        feats[slot[t]] = s * scale[t];
    }
    __syncthreads();

    // ---- fused MLP: 10 -> 64 (ReLU) -> 128 ----
    if (t < HID) {
        float acc = b1[t];
        #pragma unroll
        for (int i = 0; i < 10; i++) acc += feats[i] * W1[i * HID + t];
        hidden[t] = fmaxf(acc, 0.0f);
    }
    __syncthreads();
    if (t < OUTD) {
        float acc = b2[t];
        #pragma unroll
        for (int j = 0; j < HID; j++) acc += hidden[j] * W2[j * OUTD + t];
        out[(size_t)bt * OUTD + t] = acc;
    }
}

extern "C" void kernel_launch(void* const* d_in, const int* in_sizes, int n_in,
                              void* d_out, int out_size, void* d_ws, size_t ws_size,
                              hipStream_t stream) {
    (void)in_sizes; (void)n_in; (void)out_size; (void)ws_size;
    const float* h_in  = (const float*)d_in[0];
    const float* o_in  = (const float*)d_in[1];
    const float* sh_in = (const float*)d_in[2];
    // d_in[3] (s_o) is dead after the [:, :10] slice
    const float* W1 = (const float*)d_in[4];
    const float* b1 = (const float*)d_in[5];
    const float* W2 = (const float*)d_in[6];
    const float* b2 = (const float*)d_in[7];
    float* out = (float*)d_out;

    // workspace: Th table then To table, each BT*512 float4 = 2 MB
    float4* Th = (float4*)d_ws;
    float4* To = Th + (size_t)BT_TOT * NH;

    ie_prep<<<BT_TOT, 512, 0, stream>>>(h_in, o_in, Th, To);
    ie_main<<<BT_TOT, 512, 0, stream>>>(h_in, o_in, sh_in, Th, To,
                                        W1, b1, W2, b2, out);
}

// Round 4
// 90.659 us; speedup vs baseline: 1.2981x; 1.2981x over previous
//
#include <hip/hip_runtime.h>
#include <math.h>

#define NH 512
#define NO 512
#define BT_TOT 256
#define HID 64
#define OUTD 128

__device__ __forceinline__ float wave_sum(float v) {
    #pragma unroll
    for (int off = 32; off > 0; off >>= 1) v += __shfl_xor(v, off, 64);
    return v;
}

// Single fused kernel: 1024 threads per bt.
//  t in [0,512)   : pass1 — humans {t&255, (t&255)+256} vs objects [sh*256, sh*256+256), sh = t>>8
//  t in [512,1024): pass2 — objects {u&255, (u&255)+256} vs humans  [sh*256, ...), u = t-512
// Tables T[p] = (-2x,-2y,-2z,||p||^2) in LDS; d^2 = ||q||^2 + fma(qz,T.z,fma(qy,T.y,fma(qx,T.x,T.w)))
__global__ __launch_bounds__(1024) void ie_kernel(
    const float* __restrict__ h_in, const float* __restrict__ o_in,
    const float* __restrict__ sh_in,
    const float* __restrict__ W1, const float* __restrict__ b1,
    const float* __restrict__ W2, const float* __restrict__ b2,
    float* __restrict__ out)
{
    __shared__ float4 Th[NH];
    __shared__ float4 To[NO];
    __shared__ float  p1val[2 * NH];
    __shared__ int    p1idx[2 * NH];
    __shared__ float  p2val[2 * NO];
    __shared__ float  sdm[NH];
    __shared__ float  wred[5][8];
    __shared__ float  feats[16];
    __shared__ float  hidden[HID];

    const int bt = blockIdx.x, t = threadIdx.x;
    const int wave = t >> 6, lane = t & 63;

    // ---- build tables in LDS (one coalesced coord load per thread) ----
    if (t < NO) {
        const float* op = o_in + ((size_t)bt * NO + t) * 3;
        float x = op[0], y = op[1], z = op[2];
        To[t] = make_float4(-2.f * x, -2.f * y, -2.f * z, x * x + y * y + z * z);
    } else {
        const int hp_i = t - NO;
        const float* hp = h_in + ((size_t)bt * NH + hp_i) * 3;
        float x = hp[0], y = hp[1], z = hp[2];
        Th[hp_i] = make_float4(-2.f * x, -2.f * y, -2.f * z, x * x + y * y + z * z);
    }
    __syncthreads();

    // ---- main distance loops ----
    if (t < 512) {
        const int qb = t & 255, sh = t >> 8, mbase = sh << 8;
        float4 H0 = Th[qb], H1 = Th[qb + 256];
        const float px0 = -0.5f * H0.x, py0 = -0.5f * H0.y, pz0 = -0.5f * H0.z;
        const float px1 = -0.5f * H1.x, py1 = -0.5f * H1.y, pz1 = -0.5f * H1.z;

        float bA0 = 1e30f, bB0 = 1e30f, bC0 = 1e30f, bD0 = 1e30f;
        float bA1 = 1e30f, bB1 = 1e30f, bC1 = 1e30f, bD1 = 1e30f;
        int   iA0 = 0, iB0 = 1, iC0 = 2, iD0 = 3;
        int   iA1 = 0, iB1 = 1, iC1 = 2, iD1 = 3;

        #pragma unroll 2
        for (int m = 0; m < 256; m += 4) {
            float4 q0 = To[mbase + m],     q1 = To[mbase + m + 1];
            float4 q2 = To[mbase + m + 2], q3 = To[mbase + m + 3];

            float a00 = fmaf(pz0, q0.z, fmaf(py0, q0.y, fmaf(px0, q0.x, q0.w)));
            float a01 = fmaf(pz0, q1.z, fmaf(py0, q1.y, fmaf(px0, q1.x, q1.w)));
            float a02 = fmaf(pz0, q2.z, fmaf(py0, q2.y, fmaf(px0, q2.x, q2.w)));
            float a03 = fmaf(pz0, q3.z, fmaf(py0, q3.y, fmaf(px0, q3.x, q3.w)));
            float a10 = fmaf(pz1, q0.z, fmaf(py1, q0.y, fmaf(px1, q0.x, q0.w)));
            float a11 = fmaf(pz1, q1.z, fmaf(py1, q1.y, fmaf(px1, q1.x, q1.w)));
            float a12 = fmaf(pz1, q2.z, fmaf(py1, q2.y, fmaf(px1, q2.x, q2.w)));
            float a13 = fmaf(pz1, q3.z, fmaf(py1, q3.y, fmaf(px1, q3.x, q3.w)));

            if (a00 < bA0) { bA0 = a00; iA0 = m;     }
            if (a01 < bB0) { bB0 = a01; iB0 = m + 1; }
            if (a02 < bC0) { bC0 = a02; iC0 = m + 2; }
            if (a03 < bD0) { bD0 = a03; iD0 = m + 3; }
            if (a10 < bA1) { bA1 = a10; iA1 = m;     }
            if (a11 < bB1) { bB1 = a11; iB1 = m + 1; }
            if (a12 < bC1) { bC1 = a12; iC1 = m + 2; }
            if (a13 < bD1) { bD1 = a13; iD1 = m + 3; }
        }

        // combine trackers (residues 0<1<2<3 at equal local m-group => first-index tie-break)
        float b0 = bA0; int i0 = iA0;
        if (bB0 < b0 || (bB0 == b0 && iB0 < i0)) { b0 = bB0; i0 = iB0; }
        if (bC0 < b0 || (bC0 == b0 && iC0 < i0)) { b0 = bC0; i0 = iC0; }
        if (bD0 < b0 || (bD0 == b0 && iD0 < i0)) { b0 = bD0; i0 = iD0; }
        float b1v = bA1; int i1 = iA1;
        if (bB1 < b1v || (bB1 == b1v && iB1 < i1)) { b1v = bB1; i1 = iB1; }
        if (bC1 < b1v || (bC1 == b1v && iC1 < i1)) { b1v = bC1; i1 = iC1; }
        if (bD1 < b1v || (bD1 == b1v && iD1 < i1)) { b1v = bD1; i1 = iD1; }

        p1val[sh * NH + qb]       = b0;  p1idx[sh * NH + qb]       = mbase + i0;
        p1val[sh * NH + qb + 256] = b1v; p1idx[sh * NH + qb + 256] = mbase + i1;
    } else {
        const int u = t - 512, qb = u & 255, sh = u >> 8, nbase = sh << 8;
        float4 O0 = To[qb], O1 = To[qb + 256];
        const float qx0 = -0.5f * O0.x, qy0 = -0.5f * O0.y, qz0 = -0.5f * O0.z;
        const float qx1 = -0.5f * O1.x, qy1 = -0.5f * O1.y, qz1 = -0.5f * O1.z;

        float c0 = 1e30f, c1 = 1e30f;
        #pragma unroll 2
        for (int n = 0; n < 256; n += 4) {
            float4 r0 = Th[nbase + n],     r1 = Th[nbase + n + 1];
            float4 r2 = Th[nbase + n + 2], r3 = Th[nbase + n + 3];
            float e00 = fmaf(qz0, r0.z, fmaf(qy0, r0.y, fmaf(qx0, r0.x, r0.w)));
            float e01 = fmaf(qz0, r1.z, fmaf(qy0, r1.y, fmaf(qx0, r1.x, r1.w)));
            float e02 = fmaf(qz0, r2.z, fmaf(qy0, r2.y, fmaf(qx0, r2.x, r2.w)));
            float e03 = fmaf(qz0, r3.z, fmaf(qy0, r3.y, fmaf(qx0, r3.x, r3.w)));
            float e10 = fmaf(qz1, r0.z, fmaf(qy1, r0.y, fmaf(qx1, r0.x, r0.w)));
            float e11 = fmaf(qz1, r1.z, fmaf(qy1, r1.y, fmaf(qx1, r1.x, r1.w)));
            float e12 = fmaf(qz1, r2.z, fmaf(qy1, r2.y, fmaf(qx1, r2.x, r2.w)));
            float e13 = fmaf(qz1, r3.z, fmaf(qy1, r3.y, fmaf(qx1, r3.x, r3.w)));
            c0 = fminf(c0, fminf(fminf(e00, e01), fminf(e02, e03)));
            c1 = fminf(c1, fminf(fminf(e10, e11), fminf(e12, e13)));
        }
        p2val[sh * NO + qb]       = c0;
        p2val[sh * NO + qb + 256] = c1;
    }
    __syncthreads();

    // ---- combine halves, per-point features ----
    float v = 0.f;          // dmin_h for sort (t<512)
    float w_t = 0.f, dx = 0.f, dy = 0.f, dz = 0.f, dmo_t = 0.f;
    if (t < 512) {
        float v0 = p1val[t], v1 = p1val[NH + t];
        int   j0 = p1idx[t], j1 = p1idx[NH + t];
        float best = v0; int bm = j0;
        if (v1 < best) { best = v1; bm = j1; }  // equality keeps half0 = lower index
        float4 H = Th[t];
        const float px = -0.5f * H.x, py = -0.5f * H.y, pz = -0.5f * H.z;
        const float dmin_t = sqrtf(fmaxf(H.w + best, 0.f));
        float4 O = To[bm];
        const float vx = fmaf(-0.5f, O.x, -px), vy = fmaf(-0.5f, O.y, -py), vz = fmaf(-0.5f, O.z, -pz);
        const float n2 = vx * vx + vy * vy + vz * vz;
        const float inv = 1.0f / sqrtf(fmaxf(n2, 1e-6f));
        w_t = expf(-dmin_t * 20.0f) * sh_in[(size_t)bt * NH + t];
        dx = vx * inv; dy = vy * inv; dz = vz * inv;
        v = dmin_t;
    } else {
        const int o = t - 512;
        float c = fminf(p2val[o], p2val[NO + o]);
        dmo_t = sqrtf(fmaxf(To[o].w + c, 0.f));
    }

    // ---- reductions set 1 ----
    if (t < 512) {
        float s0 = wave_sum(w_t), s1 = wave_sum(dx), s2 = wave_sum(dy), s3 = wave_sum(dz);
        if (lane == 0) { wred[0][wave] = s0; wred[1][wave] = s1; wred[2][wave] = s2; wred[3][wave] = s3; }
    } else {
        float s4 = wave_sum(dmo_t);
        if (lane == 0) wred[4][wave - 8] = s4;
    }
    __syncthreads();
    if (t < 5) {
        float s = 0.f;
        #pragma unroll
        for (int w = 0; w < 8; w++) s += wred[t][w];
        const int slot[5] = {5, 6, 7, 8, 9};
        feats[slot[t]] = s * (1.0f / 512.0f);
    }

    // ---- bitonic sort of dmin_h (t<512); shuffles for j<64, LDS for j>=64 ----
    for (int k2 = 2; k2 <= 512; k2 <<= 1) {
        for (int j = k2 >> 1; j > 0; j >>= 1) {
            float pv;
            if (j >= 64) {
                if (t < 512) sdm[t] = v;
                __syncthreads();
                pv = (t < 512) ? sdm[t ^ j] : 0.f;
                __syncthreads();
            } else {
                pv = __shfl_xor(v, j, 64);
            }
            if (t < 512) {
                const bool keepmin = (((t & k2) == 0) == ((t & j) == 0));
                v = keepmin ? fminf(v, pv) : fmaxf(v, pv);
            }
        }
    }

    // ---- reductions set 2: prefix means over sorted dmin_h ----
    if (t < 512) {
        float s0 = wave_sum(t < 102 ? v : 0.f);
        float s1 = wave_sum(t < 256 ? v : 0.f);
        float s2 = wave_sum(t < 410 ? v : 0.f);
        float s3 = wave_sum(v);
        if (lane == 0) { wred[0][wave] = s0; wred[1][wave] = s1; wred[2][wave] = s2; wred[3][wave] = s3; }
        if (t == 0) feats[1] = v;  // sorted min
    }
    __syncthreads();
    if (t < 4) {
        float s = 0.f;
        #pragma unroll
        for (int w = 0; w < 8; w++) s += wred[t][w];
        const int   slot[4]  = {2, 3, 4, 0};
        const float scale[4] = {1.f / 102.f, 1.f / 256.f, 1.f / 410.f, 1.f / 512.f};
        feats[slot[t]] = s * scale[t];
    }
    __syncthreads();

    // ---- fused MLP: 10 -> 64 (ReLU) -> 128 ----
    if (t < HID) {
        float acc = b1[t];
        #pragma unroll
        for (int i = 0; i < 10; i++) acc += feats[i] * W1[i * HID + t];
        hidden[t] = fmaxf(acc, 0.0f);
    }
    __syncthreads();
    if (t < OUTD) {
        float acc = b2[t];
        #pragma unroll
        for (int j = 0; j < HID; j++) acc += hidden[j] * W2[j * OUTD + t];
        out[(size_t)bt * OUTD + t] = acc;
    }
}

extern "C" void kernel_launch(void* const* d_in, const int* in_sizes, int n_in,
                              void* d_out, int out_size, void* d_ws, size_t ws_size,
                              hipStream_t stream) {
    (void)in_sizes; (void)n_in; (void)out_size; (void)d_ws; (void)ws_size;
    const float* h_in  = (const float*)d_in[0];
    const float* o_in  = (const float*)d_in[1];
    const float* sh_in = (const float*)d_in[2];
    // d_in[3] (s_o) is dead after the [:, :10] slice
    const float* W1 = (const float*)d_in[4];
    const float* b1 = (const float*)d_in[5];
    const float* W2 = (const float*)d_in[6];
    const float* b2 = (const float*)d_in[7];
    float* out = (float*)d_out;

    ie_kernel<<<BT_TOT, 1024, 0, stream>>>(h_in, o_in, sh_in, W1, b1, W2, b2, out);
}

// Round 5
// 88.582 us; speedup vs baseline: 1.3285x; 1.0234x over previous
//
#include <hip/hip_runtime.h>
#include <math.h>

#define NH 512
#define NO 512
#define BT_TOT 256
#define HID 64
#define OUTD 128

__device__ __forceinline__ float wave_sum(float v) {
    #pragma unroll
    for (int off = 32; off > 0; off >>= 1) v += __shfl_xor(v, off, 64);
    return v;
}

// 1024 threads per bt. Q=8 register blocking:
//   waves 0..7  (t<512) : pass1 — thread (l=t&63, wv=t>>6) handles humans {l+64j}
//                          vs object substream [64*wv, 64*wv+64)
//   waves 8..15 (t>=512): pass2 — same decomposition, objects vs human substream
// Tables T[p]=(-2x,-2y,-2z,||p||^2) in LDS; d^2 = ||q||^2 + fma(qz,T.z,fma(qy,T.y,fma(qx,T.x,T.w)))
// Each ds_read_b128 of a table entry feeds 8 query distances (vs 2 before).
__global__ __launch_bounds__(1024) void ie_kernel(
    const float* __restrict__ h_in, const float* __restrict__ o_in,
    const float* __restrict__ sh_in,
    const float* __restrict__ W1, const float* __restrict__ b1,
    const float* __restrict__ W2, const float* __restrict__ b2,
    float* __restrict__ out)
{
    __shared__ float4 Th[NH];           // 8 KB
    __shared__ float4 To[NO];           // 8 KB
    __shared__ float  p1val[8 * NH];    // 16 KB  [wave][query]
    __shared__ int    p1idx[8 * NH];    // 16 KB
    __shared__ float  p2val[8 * NO];    // 16 KB
    __shared__ float  sdm[NH];          // 2 KB
    __shared__ float  wred[5][8];
    __shared__ float  feats[16];
    __shared__ float  hidden[HID];

    const int bt = blockIdx.x, t = threadIdx.x;
    const int wave = t >> 6, lane = t & 63;

    // ---- build tables in LDS ----
    if (t < NO) {
        const float* op = o_in + ((size_t)bt * NO + t) * 3;
        float x = op[0], y = op[1], z = op[2];
        To[t] = make_float4(-2.f * x, -2.f * y, -2.f * z, x * x + y * y + z * z);
    } else {
        const int hp_i = t - NO;
        const float* hp = h_in + ((size_t)bt * NH + hp_i) * 3;
        float x = hp[0], y = hp[1], z = hp[2];
        Th[hp_i] = make_float4(-2.f * x, -2.f * y, -2.f * z, x * x + y * y + z * z);
    }
    __syncthreads();

    // ---- main distance loops (Q=8 per thread) ----
    if (t < 512) {
        const int l = t & 63, wv = t >> 6;
        const int obase = wv << 6;
        float qx[8], qy[8], qz[8], bb[8];
        int   bi[8];
        #pragma unroll
        for (int j = 0; j < 8; j++) {
            float4 H = Th[l + 64 * j];
            qx[j] = -0.5f * H.x; qy[j] = -0.5f * H.y; qz[j] = -0.5f * H.z;
            bb[j] = 1e30f; bi[j] = obase;
        }
        for (int n = 0; n < 64; n += 4) {
            float4 o0 = To[obase + n],     o1 = To[obase + n + 1];
            float4 o2 = To[obase + n + 2], o3 = To[obase + n + 3];
            #pragma unroll
            for (int j = 0; j < 8; j++) {
                float a0 = fmaf(qz[j], o0.z, fmaf(qy[j], o0.y, fmaf(qx[j], o0.x, o0.w)));
                float a1 = fmaf(qz[j], o1.z, fmaf(qy[j], o1.y, fmaf(qx[j], o1.x, o1.w)));
                float a2 = fmaf(qz[j], o2.z, fmaf(qy[j], o2.y, fmaf(qx[j], o2.x, o2.w)));
                float a3 = fmaf(qz[j], o3.z, fmaf(qy[j], o3.y, fmaf(qx[j], o3.x, o3.w)));
                // strict < and ascending n => first-index tie-break within substream
                if (a0 < bb[j]) { bb[j] = a0; bi[j] = obase + n;     }
                if (a1 < bb[j]) { bb[j] = a1; bi[j] = obase + n + 1; }
                if (a2 < bb[j]) { bb[j] = a2; bi[j] = obase + n + 2; }
                if (a3 < bb[j]) { bb[j] = a3; bi[j] = obase + n + 3; }
            }
        }
        #pragma unroll
        for (int j = 0; j < 8; j++) {
            p1val[wv * NH + l + 64 * j] = bb[j];
            p1idx[wv * NH + l + 64 * j] = bi[j];
        }
    } else {
        const int u = t - 512, l = u & 63, wv = u >> 6;
        const int nbase = wv << 6;
        float qx[8], qy[8], qz[8], cc[8];
        #pragma unroll
        for (int j = 0; j < 8; j++) {
            float4 O = To[l + 64 * j];
            qx[j] = -0.5f * O.x; qy[j] = -0.5f * O.y; qz[j] = -0.5f * O.z;
            cc[j] = 1e30f;
        }
        for (int n = 0; n < 64; n += 4) {
            float4 r0 = Th[nbase + n],     r1 = Th[nbase + n + 1];
            float4 r2 = Th[nbase + n + 2], r3 = Th[nbase + n + 3];
            #pragma unroll
            for (int j = 0; j < 8; j++) {
                float e0 = fmaf(qz[j], r0.z, fmaf(qy[j], r0.y, fmaf(qx[j], r0.x, r0.w)));
                float e1 = fmaf(qz[j], r1.z, fmaf(qy[j], r1.y, fmaf(qx[j], r1.x, r1.w)));
                float e2 = fmaf(qz[j], r2.z, fmaf(qy[j], r2.y, fmaf(qx[j], r2.x, r2.w)));
                float e3 = fmaf(qz[j], r3.z, fmaf(qy[j], r3.y, fmaf(qx[j], r3.x, r3.w)));
                cc[j] = fminf(cc[j], fminf(fminf(e0, e1), fminf(e2, e3)));
            }
        }
        #pragma unroll
        for (int j = 0; j < 8; j++) p2val[wv * NO + l + 64 * j] = cc[j];
    }
    __syncthreads();

    // ---- combine 8 substream partials per point, per-point features ----
    float v = 0.f;          // dmin_h for sort (t<512)
    float w_t = 0.f, dx = 0.f, dy = 0.f, dz = 0.f, dmo_t = 0.f;
    if (t < 512) {
        float best = p1val[t]; int bm = p1idx[t];
        #pragma unroll
        for (int w = 1; w < 8; w++) {
            float pv = p1val[w * NH + t];
            int   pi = p1idx[w * NH + t];
            if (pv < best) { best = pv; bm = pi; }  // strict <, ascending w => lowest index on tie
        }
        float4 H = Th[t];
        const float px = -0.5f * H.x, py = -0.5f * H.y, pz = -0.5f * H.z;
        const float dmin_t = sqrtf(fmaxf(H.w + best, 0.f));
        float4 O = To[bm];
        const float vx = fmaf(-0.5f, O.x, -px), vy = fmaf(-0.5f, O.y, -py), vz = fmaf(-0.5f, O.z, -pz);
        const float n2 = vx * vx + vy * vy + vz * vz;
        const float inv = 1.0f / sqrtf(fmaxf(n2, 1e-6f));
        w_t = expf(-dmin_t * 20.0f) * sh_in[(size_t)bt * NH + t];
        dx = vx * inv; dy = vy * inv; dz = vz * inv;
        v = dmin_t;
    } else {
        const int o = t - 512;
        float c = p2val[o];
        #pragma unroll
        for (int w = 1; w < 8; w++) c = fminf(c, p2val[w * NO + o]);
        dmo_t = sqrtf(fmaxf(To[o].w + c, 0.f));
    }

    // ---- reductions set 1 ----
    if (t < 512) {
        float s0 = wave_sum(w_t), s1 = wave_sum(dx), s2 = wave_sum(dy), s3 = wave_sum(dz);
        if (lane == 0) { wred[0][wave] = s0; wred[1][wave] = s1; wred[2][wave] = s2; wred[3][wave] = s3; }
    } else {
        float s4 = wave_sum(dmo_t);
        if (lane == 0) wred[4][wave - 8] = s4;
    }
    __syncthreads();
    if (t < 5) {
        float s = 0.f;
        #pragma unroll
        for (int w = 0; w < 8; w++) s += wred[t][w];
        const int slot[5] = {5, 6, 7, 8, 9};
        feats[slot[t]] = s * (1.0f / 512.0f);
    }

    // ---- bitonic sort of dmin_h (t<512); shuffles for j<64, LDS for j>=64 ----
    for (int k2 = 2; k2 <= 512; k2 <<= 1) {
        for (int j = k2 >> 1; j > 0; j >>= 1) {
            float pv;
            if (j >= 64) {
                if (t < 512) sdm[t] = v;
                __syncthreads();
                pv = (t < 512) ? sdm[t ^ j] : 0.f;
                __syncthreads();
            } else {
                pv = __shfl_xor(v, j, 64);
            }
            if (t < 512) {
                const bool keepmin = (((t & k2) == 0) == ((t & j) == 0));
                v = keepmin ? fminf(v, pv) : fmaxf(v, pv);
            }
        }
    }

    // ---- reductions set 2: prefix means over sorted dmin_h ----
    if (t < 512) {
        float s0 = wave_sum(t < 102 ? v : 0.f);
        float s1 = wave_sum(t < 256 ? v : 0.f);
        float s2 = wave_sum(t < 410 ? v : 0.f);
        float s3 = wave_sum(v);
        if (lane == 0) { wred[0][wave] = s0; wred[1][wave] = s1; wred[2][wave] = s2; wred[3][wave] = s3; }
        if (t == 0) feats[1] = v;  // sorted min
    }
    __syncthreads();
    if (t < 4) {
        float s = 0.f;
        #pragma unroll
        for (int w = 0; w < 8; w++) s += wred[t][w];
        const int   slot[4]  = {2, 3, 4, 0};
        const float scale[4] = {1.f / 102.f, 1.f / 256.f, 1.f / 410.f, 1.f / 512.f};
        feats[slot[t]] = s * scale[t];
    }
    __syncthreads();

    // ---- fused MLP: 10 -> 64 (ReLU) -> 128 ----
    if (t < HID) {
        float acc = b1[t];
        #pragma unroll
        for (int i = 0; i < 10; i++) acc += feats[i] * W1[i * HID + t];
        hidden[t] = fmaxf(acc, 0.0f);
    }
    __syncthreads();
    if (t < OUTD) {
        float acc = b2[t];
        #pragma unroll
        for (int j = 0; j < HID; j++) acc += hidden[j] * W2[j * OUTD + t];
        out[(size_t)bt * OUTD + t] = acc;
    }
}

extern "C" void kernel_launch(void* const* d_in, const int* in_sizes, int n_in,
                              void* d_out, int out_size, void* d_ws, size_t ws_size,
                              hipStream_t stream) {
    (void)in_sizes; (void)n_in; (void)out_size; (void)d_ws; (void)ws_size;
    const float* h_in  = (const float*)d_in[0];
    const float* o_in  = (const float*)d_in[1];
    const float* sh_in = (const float*)d_in[2];
    // d_in[3] (s_o) is dead after the [:, :10] slice
    const float* W1 = (const float*)d_in[4];
    const float* b1 = (const float*)d_in[5];
    const float* W2 = (const float*)d_in[6];
    const float* b2 = (const float*)d_in[7];
    float* out = (float*)d_out;

    ie_kernel<<<BT_TOT, 1024, 0, stream>>>(h_in, o_in, sh_in, W1, b1, W2, b2, out);
}